// Round 1
// baseline (462.575 us; speedup 1.0000x reference)
//
#include <hip/hip_runtime.h>

// CrissCrossAttention: B=8 C=512 CQ=128 H=W=96
// ws layout (bytes), total 189,530,112 (overlaid regions, launch order enforces lifetimes):
//  R0 @0         (75,497,472): xT[b][hw][c]bf16 -> att_f32[b][h][w][192] -> Vt[b][c][w][h]bf16
//  R1 @75497472  (75,497,472): Vn[b][c][h][w]bf16 -> tmpHT[b][c][w][h]bf16
//  R2 @150994944 (37,748,736): Qb[p][128]bf16 | Kb[p][128]bf16 -> att2[b][h][w][192]bf16
//  R3 @188743680 (   786,432): Wqk bf16[256][512], Wv bf16[512][512]

#define B_ 8
#define C_ 512
#define CQ_ 128
#define H_ 96
#define W_ 96
#define HW_ 9216
#define J_ 192

typedef __attribute__((ext_vector_type(8))) short short8;
typedef __attribute__((ext_vector_type(4))) float f32x4;

__device__ __forceinline__ unsigned short f2bf(float f) {
    unsigned u = __float_as_uint(f);
    u += 0x7FFFu + ((u >> 16) & 1u);
    return (unsigned short)(u >> 16);
}
__device__ __forceinline__ float bf2f(unsigned short h) {
    return __uint_as_float((unsigned)h << 16);
}

// ---------------- K0: weights fp32 -> bf16 (fused Wq|Wk, Wv) ----------------
__global__ __launch_bounds__(256) void k0_wconv(const float* __restrict__ Wq,
                                                const float* __restrict__ Wk,
                                                const float* __restrict__ Wv,
                                                unsigned short* __restrict__ Wqk,
                                                unsigned short* __restrict__ Wvb) {
    int i = blockIdx.x * 256 + threadIdx.x;          // grid 1536*256 = 393216 exact
    if (i < 65536)        Wqk[i] = f2bf(Wq[i]);
    else if (i < 131072)  Wqk[i] = f2bf(Wk[i - 65536]);
    else                  Wvb[i - 131072] = f2bf(Wv[i - 131072]);
}

// ---------------- K1: x[b][c][h][w] f32 -> xT[b][hw][c] bf16 ----------------
__global__ __launch_bounds__(256) void k1_xT(const float* __restrict__ x,
                                             unsigned short* __restrict__ xT) {
    __shared__ unsigned short t[32][33];
    int b = blockIdx.z, c0 = blockIdx.y * 32, p0 = blockIdx.x * 32;
    int tx = threadIdx.x, ty = threadIdx.y;
    const float* xb = x + (size_t)b * C_ * HW_;
    #pragma unroll
    for (int k = 0; k < 4; ++k) {
        int c = c0 + ty + k * 8;
        t[ty + k * 8][tx] = f2bf(xb[(size_t)c * HW_ + p0 + tx]);
    }
    __syncthreads();
    unsigned short* xTb = xT + (size_t)b * HW_ * C_;
    #pragma unroll
    for (int k = 0; k < 4; ++k) {
        int p = p0 + ty + k * 8;
        xTb[(size_t)p * C_ + c0 + tx] = t[tx][ty + k * 8];
    }
}

// ---------------- K2a: Q,K projection. D[p][oc]=sum_c xT[p][c]*Wqk[oc][c]+b ----------------
// BM=128(p) BN=256(oc,all) BK=64, 8 waves (2x4 of 64x64)
__global__ __launch_bounds__(512) void k2a_qk(const unsigned short* __restrict__ xT,
                                              const unsigned short* __restrict__ Wqk,
                                              const float* __restrict__ bq,
                                              const float* __restrict__ bk,
                                              unsigned short* __restrict__ Qb,
                                              unsigned short* __restrict__ Kb) {
    __shared__ alignas(16) unsigned short As[128][72];   // +8 pad: 2-way LDS conflict (free)
    __shared__ alignas(16) unsigned short Bs[256][72];
    int t = threadIdx.x;
    int p0 = blockIdx.x * 128;
    int wid = t >> 6, lane = t & 63;
    int wr = wid >> 2, wc = wid & 3;
    const f32x4 zero = {0.f, 0.f, 0.f, 0.f};
    f32x4 acc[4][4];
    for (int m = 0; m < 4; ++m) for (int n = 0; n < 4; ++n) acc[m][n] = zero;
    for (int ks = 0; ks < 512; ks += 64) {
        #pragma unroll
        for (int s = 0; s < 2; ++s) {
            int q = t + s * 512; int row = q >> 3, c8 = (q & 7) << 3;
            *(uint4*)(&As[row][c8]) = *(const uint4*)(xT + ((size_t)(p0 + row) << 9) + ks + c8);
        }
        #pragma unroll
        for (int s = 0; s < 4; ++s) {
            int q = t + s * 512; int row = q >> 3, c8 = (q & 7) << 3;
            *(uint4*)(&Bs[row][c8]) = *(const uint4*)(Wqk + ((size_t)row << 9) + ks + c8);
        }
        __syncthreads();
        #pragma unroll
        for (int kk = 0; kk < 2; ++kk) {
            int ko = (kk << 5) + ((lane >> 4) << 3);
            short8 af[4], bfv[4];
            #pragma unroll
            for (int m = 0; m < 4; ++m) af[m] = *(const short8*)(&As[wr * 64 + m * 16 + (lane & 15)][ko]);
            #pragma unroll
            for (int n = 0; n < 4; ++n) bfv[n] = *(const short8*)(&Bs[wc * 64 + n * 16 + (lane & 15)][ko]);
            #pragma unroll
            for (int m = 0; m < 4; ++m)
                #pragma unroll
                for (int n = 0; n < 4; ++n)
                    acc[m][n] = __builtin_amdgcn_mfma_f32_16x16x32_bf16(af[m], bfv[n], acc[m][n], 0, 0, 0);
        }
        __syncthreads();
    }
    #pragma unroll
    for (int n = 0; n < 4; ++n) {
        int oc = wc * 64 + n * 16 + (lane & 15);
        float bias = (oc < 128) ? bq[oc] : bk[oc - 128];
        unsigned short* dst = (oc < 128) ? (Qb + oc) : (Kb + (oc - 128));
        #pragma unroll
        for (int m = 0; m < 4; ++m) {
            int pr = p0 + wr * 64 + m * 16 + ((lane >> 4) << 2);
            #pragma unroll
            for (int r = 0; r < 4; ++r)
                dst[(size_t)(pr + r) << 7] = f2bf(acc[m][n][r] + bias);
        }
    }
}

// ---------------- K2b: V projection. D[oc][p]=sum_c Wv[oc][c]*xT[p][c]+bv -> Vn[b][c][hw] ----------------
// BM=256(oc) BN=128(p) BK=64, 8 waves (4x2 of 64x64)
__global__ __launch_bounds__(512) void k2b_v(const unsigned short* __restrict__ xT,
                                             const unsigned short* __restrict__ Wvb,
                                             const float* __restrict__ bv,
                                             unsigned short* __restrict__ Vn) {
    __shared__ alignas(16) unsigned short As[256][72];
    __shared__ alignas(16) unsigned short Bs[128][72];
    int t = threadIdx.x;
    int oc0 = blockIdx.x * 256;
    int p0 = blockIdx.y * 128;
    int wid = t >> 6, lane = t & 63;
    int wr = wid >> 1, wc = wid & 1;
    const f32x4 zero = {0.f, 0.f, 0.f, 0.f};
    f32x4 acc[4][4];
    for (int m = 0; m < 4; ++m) for (int n = 0; n < 4; ++n) acc[m][n] = zero;
    for (int ks = 0; ks < 512; ks += 64) {
        #pragma unroll
        for (int s = 0; s < 4; ++s) {
            int q = t + s * 512; int row = q >> 3, c8 = (q & 7) << 3;
            *(uint4*)(&As[row][c8]) = *(const uint4*)(Wvb + ((size_t)(oc0 + row) << 9) + ks + c8);
        }
        #pragma unroll
        for (int s = 0; s < 2; ++s) {
            int q = t + s * 512; int row = q >> 3, c8 = (q & 7) << 3;
            *(uint4*)(&Bs[row][c8]) = *(const uint4*)(xT + ((size_t)(p0 + row) << 9) + ks + c8);
        }
        __syncthreads();
        #pragma unroll
        for (int kk = 0; kk < 2; ++kk) {
            int ko = (kk << 5) + ((lane >> 4) << 3);
            short8 af[4], bfv[4];
            #pragma unroll
            for (int m = 0; m < 4; ++m) af[m] = *(const short8*)(&As[wr * 64 + m * 16 + (lane & 15)][ko]);
            #pragma unroll
            for (int n = 0; n < 4; ++n) bfv[n] = *(const short8*)(&Bs[wc * 64 + n * 16 + (lane & 15)][ko]);
            #pragma unroll
            for (int m = 0; m < 4; ++m)
                #pragma unroll
                for (int n = 0; n < 4; ++n)
                    acc[m][n] = __builtin_amdgcn_mfma_f32_16x16x32_bf16(af[m], bfv[n], acc[m][n], 0, 0, 0);
        }
        __syncthreads();
    }
    int b = p0 / HW_;
    int hw0 = p0 - b * HW_;
    #pragma unroll
    for (int m = 0; m < 4; ++m) {
        int ocb = oc0 + wr * 64 + m * 16 + ((lane >> 4) << 2);
        #pragma unroll
        for (int n = 0; n < 4; ++n) {
            int hw = hw0 + wc * 64 + n * 16 + (lane & 15);
            #pragma unroll
            for (int r = 0; r < 4; ++r) {
                int oc = ocb + r;
                Vn[(size_t)(b * C_ + oc) * HW_ + hw] = f2bf(acc[m][n][r] + bv[oc]);
            }
        }
    }
}

// ---------------- K3: Vn[b][c][h][w] -> Vt[b][c][w][h] (bf16 plane transpose) ----------------
__global__ __launch_bounds__(256) void k3_vt(const unsigned short* __restrict__ Vn,
                                             unsigned short* __restrict__ Vt) {
    __shared__ unsigned short tl[96][97];
    int plane = blockIdx.x;                         // b*512+c
    const unsigned short* src = Vn + (size_t)plane * HW_;
    unsigned short* dst = Vt + (size_t)plane * HW_;
    for (int e = threadIdx.x; e < HW_; e += 256) tl[e / 96][e % 96] = src[e];
    __syncthreads();
    for (int e = threadIdx.x; e < HW_; e += 256) { int w = e / 96, h = e % 96; dst[e] = tl[h][w]; }
}

// ---------------- K4: energies. z=0: E_W per (b,h); z=1: E_H per (b,w) (diag -> -inf) ----------------
__global__ __launch_bounds__(256) void k4_energy(const unsigned short* __restrict__ Qb,
                                                 const unsigned short* __restrict__ Kb,
                                                 float* __restrict__ att) {
    __shared__ alignas(16) unsigned short Qs[96][136];
    __shared__ alignas(16) unsigned short Ks[96][136];
    int t = threadIdx.x;
    int modeH = blockIdx.z;
    int b = blockIdx.y, v0 = blockIdx.x;
    size_t base, rstride, obase_off, ostride;
    if (!modeH) {               // rows i=w at fixed (b,h=v0): consecutive pixels
        base      = (size_t)((b * H_ + v0) * W_) * CQ_;
        rstride   = CQ_;
        obase_off = (size_t)((b * H_ + v0) * W_) * J_ + H_;   // att[b][v0][i][96+j]
        ostride   = J_;
    } else {                    // rows i=h at fixed (b,w=v0): stride W*CQ
        base      = ((size_t)(b * H_) * W_ + v0) * CQ_;
        rstride   = (size_t)W_ * CQ_;
        obase_off = ((size_t)(b * H_) * W_ + v0) * J_;        // att[b][i][v0][j]
        ostride   = (size_t)W_ * J_;
    }
    for (int q = t; q < 1536; q += 256) {
        int row = q >> 4, c8 = (q & 15) << 3;
        *(uint4*)(&Qs[row][c8]) = *(const uint4*)(Qb + base + (size_t)row * rstride + c8);
        *(uint4*)(&Ks[row][c8]) = *(const uint4*)(Kb + base + (size_t)row * rstride + c8);
    }
    __syncthreads();
    int wid = t >> 6, lane = t & 63;
    int wr = wid >> 1, wc = wid & 1;                 // 2x2 waves of 48x48
    const f32x4 zero = {0.f, 0.f, 0.f, 0.f};
    f32x4 acc[3][3];
    for (int m = 0; m < 3; ++m) for (int n = 0; n < 3; ++n) acc[m][n] = zero;
    #pragma unroll
    for (int ks = 0; ks < 128; ks += 32) {
        int ko = ks + ((lane >> 4) << 3);
        short8 af[3], bfv[3];
        #pragma unroll
        for (int m = 0; m < 3; ++m) af[m] = *(const short8*)(&Qs[wr * 48 + m * 16 + (lane & 15)][ko]);
        #pragma unroll
        for (int n = 0; n < 3; ++n) bfv[n] = *(const short8*)(&Ks[wc * 48 + n * 16 + (lane & 15)][ko]);
        #pragma unroll
        for (int m = 0; m < 3; ++m)
            #pragma unroll
            for (int n = 0; n < 3; ++n)
                acc[m][n] = __builtin_amdgcn_mfma_f32_16x16x32_bf16(af[m], bfv[n], acc[m][n], 0, 0, 0);
    }
    float* ob = att + obase_off;
    #pragma unroll
    for (int m = 0; m < 3; ++m) {
        int i = wr * 48 + m * 16 + ((lane >> 4) << 2);
        #pragma unroll
        for (int n = 0; n < 3; ++n) {
            int j = wc * 48 + n * 16 + (lane & 15);
            #pragma unroll
            for (int r = 0; r < 4; ++r) {
                float v = acc[m][n][r];
                if (modeH && (i + r) == j) v = -__builtin_inff();
                ob[(size_t)(i + r) * ostride + j] = v;
            }
        }
    }
}

// ---------------- K5: softmax over 192, fp32 -> bf16 att2 (one wave per row) ----------------
__global__ __launch_bounds__(256) void k5_softmax(const float* __restrict__ att,
                                                  unsigned short* __restrict__ att2) {
    int r = blockIdx.x * 4 + (threadIdx.x >> 6);
    int lane = threadIdx.x & 63;
    const float* row = att + (size_t)r * J_;
    float e0 = row[lane], e1 = row[lane + 64], e2 = row[lane + 128];
    float m = fmaxf(e0, fmaxf(e1, e2));
    #pragma unroll
    for (int off = 32; off; off >>= 1) m = fmaxf(m, __shfl_xor(m, off, 64));
    float p0 = __expf(e0 - m), p1 = __expf(e1 - m), p2 = __expf(e2 - m);
    float s = p0 + p1 + p2;
    #pragma unroll
    for (int off = 32; off; off >>= 1) s += __shfl_xor(s, off, 64);
    float inv = 1.f / s;
    unsigned short* orow = att2 + (size_t)r * J_;
    orow[lane]       = f2bf(p0 * inv);
    orow[lane + 64]  = f2bf(p1 * inv);
    orow[lane + 128] = f2bf(p2 * inv);
}

// ---------------- K6/K7: aggregation GEMMs, M=512(c) N=96 K=96 per (b, h|w) ----------------
// MODE 0: out_W per (b,h): D[c][w] = sum_j Vn[b][c][h][j]*attW ; write out = gamma*D + x
// MODE 1: out_H per (b,w): D[c][h] = sum_j Vt[b][c][w][j]*attH ; write tmpHT[b][c][w][h] bf16
template <int MODE>
__global__ __launch_bounds__(256) void k67_agg(const unsigned short* __restrict__ Vsrc,
                                               const unsigned short* __restrict__ att2,
                                               const float* __restrict__ xin,
                                               const float* __restrict__ gamma_p,
                                               float* __restrict__ outp,
                                               unsigned short* __restrict__ tmpHT) {
    __shared__ alignas(16) unsigned short As[128][104];
    __shared__ alignas(16) unsigned short Bs[96][104];
    int t = threadIdx.x;
    int c0 = blockIdx.x * 128;
    int b = blockIdx.y / 96;
    int v0 = blockIdx.y % 96;
    size_t abase, bbase, bstride;
    if (MODE == 0) {
        abase = (size_t)(b * C_ + c0) * HW_ + (size_t)v0 * W_;
        bbase = (size_t)((b * H_ + v0) * W_) * J_ + H_;
        bstride = J_;
    } else {
        abase = ((size_t)(b * C_ + c0) * W_ + v0) * H_;
        bbase = ((size_t)(b * H_) * W_ + v0) * J_;
        bstride = (size_t)W_ * J_;
    }
    {
        int row = t >> 1, cs = (t & 1) * 6;
        const unsigned short* src = Vsrc + abase + (size_t)row * HW_;
        #pragma unroll
        for (int i = 0; i < 6; ++i)
            *(uint4*)(&As[row][(cs + i) * 8]) = *(const uint4*)(src + (cs + i) * 8);
    }
    if (t < 192) {
        int row = t >> 1, cs = (t & 1) * 6;
        const unsigned short* src = att2 + bbase + (size_t)row * bstride;
        #pragma unroll
        for (int i = 0; i < 6; ++i)
            *(uint4*)(&Bs[row][(cs + i) * 8]) = *(const uint4*)(src + (cs + i) * 8);
    }
    __syncthreads();
    int wid = t >> 6, lane = t & 63;               // 4 waves, each 32 rows x 96 cols
    const f32x4 zero = {0.f, 0.f, 0.f, 0.f};
    f32x4 acc[2][6];
    for (int m = 0; m < 2; ++m) for (int n = 0; n < 6; ++n) acc[m][n] = zero;
    #pragma unroll
    for (int ks = 0; ks < 96; ks += 32) {
        int ko = ks + ((lane >> 4) << 3);
        short8 af[2], bfv[6];
        #pragma unroll
        for (int m = 0; m < 2; ++m) af[m] = *(const short8*)(&As[wid * 32 + m * 16 + (lane & 15)][ko]);
        #pragma unroll
        for (int n = 0; n < 6; ++n) bfv[n] = *(const short8*)(&Bs[n * 16 + (lane & 15)][ko]);
        #pragma unroll
        for (int m = 0; m < 2; ++m)
            #pragma unroll
            for (int n = 0; n < 6; ++n)
                acc[m][n] = __builtin_amdgcn_mfma_f32_16x16x32_bf16(af[m], bfv[n], acc[m][n], 0, 0, 0);
    }
    float g = gamma_p[0];
    #pragma unroll
    for (int m = 0; m < 2; ++m) {
        int cb = c0 + wid * 32 + m * 16 + ((lane >> 4) << 2);
        #pragma unroll
        for (int n = 0; n < 6; ++n) {
            int col = n * 16 + (lane & 15);
            #pragma unroll
            for (int r = 0; r < 4; ++r) {
                int c = cb + r;
                if (MODE == 0) {
                    size_t o = ((size_t)(b * C_ + c) * H_ + v0) * W_ + col;
                    outp[o] = g * acc[m][n][r] + xin[o];
                } else {
                    size_t o = ((size_t)(b * C_ + c) * W_ + v0) * H_ + col;
                    tmpHT[o] = f2bf(acc[m][n][r]);
                }
            }
        }
    }
}

// ---------------- K8: out[b][c][h][w] += gamma * tmpHT[b][c][w][h] ----------------
__global__ __launch_bounds__(256) void k8_add(const unsigned short* __restrict__ tmpHT,
                                              const float* __restrict__ gamma_p,
                                              float* __restrict__ outp) {
    __shared__ unsigned short tl[96][97];
    int plane = blockIdx.x;                          // b*512+c
    const unsigned short* src = tmpHT + (size_t)plane * HW_;   // [w][h]
    float* dst = outp + (size_t)plane * HW_;                    // [h][w]
    float g = gamma_p[0];
    for (int e = threadIdx.x; e < HW_; e += 256) tl[e / 96][e % 96] = src[e];
    __syncthreads();
    for (int e = threadIdx.x; e < HW_; e += 256) {
        int h = e / 96, w = e % 96;
        dst[e] += g * bf2f(tl[w][h]);
    }
}

extern "C" void kernel_launch(void* const* d_in, const int* in_sizes, int n_in,
                              void* d_out, int out_size, void* d_ws, size_t ws_size,
                              hipStream_t stream) {
    const float* x  = (const float*)d_in[0];
    const float* Wq = (const float*)d_in[1];
    const float* bq = (const float*)d_in[2];
    const float* Wk = (const float*)d_in[3];
    const float* bk = (const float*)d_in[4];
    const float* Wv = (const float*)d_in[5];
    const float* bv = (const float*)d_in[6];
    const float* gm = (const float*)d_in[7];
    float* out = (float*)d_out;
    char* ws = (char*)d_ws;

    unsigned short* xT    = (unsigned short*)(ws + 0);
    float*          attf  = (float*)(ws + 0);                    // after k2b done
    unsigned short* Vt    = (unsigned short*)(ws + 0);           // after k5 done
    unsigned short* Vn    = (unsigned short*)(ws + 75497472);
    unsigned short* tmpHT = (unsigned short*)(ws + 75497472);    // after k67<0> done
    unsigned short* Qb    = (unsigned short*)(ws + 150994944);
    unsigned short* Kb    = (unsigned short*)(ws + 169869312);
    unsigned short* att2  = (unsigned short*)(ws + 150994944);   // after k4 done
    unsigned short* Wqk   = (unsigned short*)(ws + 188743680);
    unsigned short* Wvb   = (unsigned short*)(ws + 189005824);
    // total ws need: 189,530,112 bytes

    k0_wconv<<<1536, 256, 0, stream>>>(Wq, Wk, Wv, Wqk, Wvb);
    k1_xT<<<dim3(288, 16, 8), dim3(32, 8, 1), 0, stream>>>(x, xT);
    k2a_qk<<<576, 512, 0, stream>>>(xT, Wqk, bq, bk, Qb, Kb);
    k2b_v<<<dim3(2, 576), 512, 0, stream>>>(xT, Wvb, bv, Vn);
    k4_energy<<<dim3(96, 8, 2), 256, 0, stream>>>(Qb, Kb, attf);   // attf overwrites xT (dead)
    k5_softmax<<<18432, 256, 0, stream>>>(attf, att2);             // att2 overwrites Q/K (dead)
    k3_vt<<<4096, 256, 0, stream>>>(Vn, Vt);                       // Vt overwrites attf (dead)
    k67_agg<0><<<dim3(4, 768), 256, 0, stream>>>(Vn, att2, x, gm, out, nullptr);
    k67_agg<1><<<dim3(4, 768), 256, 0, stream>>>(Vt, att2, x, gm, out, tmpHT); // tmpHT over Vn (dead)
    k8_add<<<4096, 256, 0, stream>>>(tmpHT, gm, out);
}

// Round 2
// 390.051 us; speedup vs baseline: 1.1859x; 1.1859x over previous
//
#include <hip/hip_runtime.h>

// CrissCrossAttention: B=8 C=512 CQ=128 H=W=96
// ws layout (bytes), total 189,530,112 (overlaid, launch order enforces lifetimes):
//  R0 @0         (75,497,472): xT[b][hw][c]bf16 -> att_f16[b][h][w][192] -> Vt[b][c][w][h]bf16 -> tmpHT (in-place)
//  R1 @75497472  (75,497,472): Vn[b][c][h][w]bf16 -> tmpW (in-place)
//  R2 @150994944 (37,748,736): Qb[p][128]bf16 | Kb[p][128]bf16 -> att2[b][h][w][192]bf16
//  R3 @188743680 (   786,432): Wqk bf16[256][512], Wv bf16[512][512]

#define B_ 8
#define C_ 512
#define CQ_ 128
#define H_ 96
#define W_ 96
#define HW_ 9216
#define J_ 192

typedef __attribute__((ext_vector_type(8))) short short8;
typedef __attribute__((ext_vector_type(4))) float f32x4;

__device__ __forceinline__ unsigned short f2bf(float f) {
    unsigned u = __float_as_uint(f);
    u += 0x7FFFu + ((u >> 16) & 1u);
    return (unsigned short)(u >> 16);
}
__device__ __forceinline__ float bf2f(unsigned short h) {
    return __uint_as_float((unsigned)h << 16);
}
__device__ __forceinline__ unsigned short f2h(float f) {
    _Float16 h = (_Float16)f;
    return __builtin_bit_cast(unsigned short, h);
}
__device__ __forceinline__ float h2f(unsigned short u) {
    return (float)__builtin_bit_cast(_Float16, u);
}

// ---------------- K0: weights fp32 -> bf16 (fused Wq|Wk, Wv) ----------------
__global__ __launch_bounds__(256) void k0_wconv(const float* __restrict__ Wq,
                                                const float* __restrict__ Wk,
                                                const float* __restrict__ Wv,
                                                unsigned short* __restrict__ Wqk,
                                                unsigned short* __restrict__ Wvb) {
    int i = blockIdx.x * 256 + threadIdx.x;          // grid 1536*256 = 393216 exact
    if (i < 65536)        Wqk[i] = f2bf(Wq[i]);
    else if (i < 131072)  Wqk[i] = f2bf(Wk[i - 65536]);
    else                  Wvb[i - 131072] = f2bf(Wv[i - 131072]);
}

// ---------------- K1: x[b][c][h][w] f32 -> xT[b][hw][c] bf16 ----------------
__global__ __launch_bounds__(256) void k1_xT(const float* __restrict__ x,
                                             unsigned short* __restrict__ xT) {
    __shared__ unsigned short t[32][33];
    int b = blockIdx.z, c0 = blockIdx.y * 32, p0 = blockIdx.x * 32;
    int tx = threadIdx.x, ty = threadIdx.y;
    const float* xb = x + (size_t)b * C_ * HW_;
    #pragma unroll
    for (int k = 0; k < 4; ++k) {
        int c = c0 + ty + k * 8;
        t[ty + k * 8][tx] = f2bf(xb[(size_t)c * HW_ + p0 + tx]);
    }
    __syncthreads();
    unsigned short* xTb = xT + (size_t)b * HW_ * C_;
    #pragma unroll
    for (int k = 0; k < 4; ++k) {
        int p = p0 + ty + k * 8;
        xTb[(size_t)p * C_ + c0 + tx] = t[tx][ty + k * 8];
    }
}

// ---------------- K2a: Q,K projection. D[p][oc]=sum_c xT[p][c]*Wqk[oc][c]+b ----------------
__global__ __launch_bounds__(512) void k2a_qk(const unsigned short* __restrict__ xT,
                                              const unsigned short* __restrict__ Wqk,
                                              const float* __restrict__ bq,
                                              const float* __restrict__ bk,
                                              unsigned short* __restrict__ Qb,
                                              unsigned short* __restrict__ Kb) {
    __shared__ alignas(16) unsigned short As[128][72];
    __shared__ alignas(16) unsigned short Bs[256][72];
    int t = threadIdx.x;
    int p0 = blockIdx.x * 128;
    int wid = t >> 6, lane = t & 63;
    int wr = wid >> 2, wc = wid & 3;
    const f32x4 zero = {0.f, 0.f, 0.f, 0.f};
    f32x4 acc[4][4];
    for (int m = 0; m < 4; ++m) for (int n = 0; n < 4; ++n) acc[m][n] = zero;
    for (int ks = 0; ks < 512; ks += 64) {
        #pragma unroll
        for (int s = 0; s < 2; ++s) {
            int q = t + s * 512; int row = q >> 3, c8 = (q & 7) << 3;
            *(uint4*)(&As[row][c8]) = *(const uint4*)(xT + ((size_t)(p0 + row) << 9) + ks + c8);
        }
        #pragma unroll
        for (int s = 0; s < 4; ++s) {
            int q = t + s * 512; int row = q >> 3, c8 = (q & 7) << 3;
            *(uint4*)(&Bs[row][c8]) = *(const uint4*)(Wqk + ((size_t)row << 9) + ks + c8);
        }
        __syncthreads();
        #pragma unroll
        for (int kk = 0; kk < 2; ++kk) {
            int ko = (kk << 5) + ((lane >> 4) << 3);
            short8 af[4], bfv[4];
            #pragma unroll
            for (int m = 0; m < 4; ++m) af[m] = *(const short8*)(&As[wr * 64 + m * 16 + (lane & 15)][ko]);
            #pragma unroll
            for (int n = 0; n < 4; ++n) bfv[n] = *(const short8*)(&Bs[wc * 64 + n * 16 + (lane & 15)][ko]);
            #pragma unroll
            for (int m = 0; m < 4; ++m)
                #pragma unroll
                for (int n = 0; n < 4; ++n)
                    acc[m][n] = __builtin_amdgcn_mfma_f32_16x16x32_bf16(af[m], bfv[n], acc[m][n], 0, 0, 0);
        }
        __syncthreads();
    }
    #pragma unroll
    for (int n = 0; n < 4; ++n) {
        int oc = wc * 64 + n * 16 + (lane & 15);
        float bias = (oc < 128) ? bq[oc] : bk[oc - 128];
        unsigned short* dst = (oc < 128) ? (Qb + oc) : (Kb + (oc - 128));
        #pragma unroll
        for (int m = 0; m < 4; ++m) {
            int pr = p0 + wr * 64 + m * 16 + ((lane >> 4) << 2);
            #pragma unroll
            for (int r = 0; r < 4; ++r)
                dst[(size_t)(pr + r) << 7] = f2bf(acc[m][n][r] + bias);
        }
    }
}

// ---------------- K2b: V projection. D[oc][p]=sum_c Wv[oc][c]*xT[p][c]+bv -> Vn[b][c][hw] ----------------
__global__ __launch_bounds__(512) void k2b_v(const unsigned short* __restrict__ xT,
                                             const unsigned short* __restrict__ Wvb,
                                             const float* __restrict__ bv,
                                             unsigned short* __restrict__ Vn) {
    __shared__ alignas(16) unsigned short As[256][72];
    __shared__ alignas(16) unsigned short Bs[128][72];
    int t = threadIdx.x;
    int oc0 = blockIdx.x * 256;
    int p0 = blockIdx.y * 128;
    int wid = t >> 6, lane = t & 63;
    int wr = wid >> 1, wc = wid & 1;
    const f32x4 zero = {0.f, 0.f, 0.f, 0.f};
    f32x4 acc[4][4];
    for (int m = 0; m < 4; ++m) for (int n = 0; n < 4; ++n) acc[m][n] = zero;
    for (int ks = 0; ks < 512; ks += 64) {
        #pragma unroll
        for (int s = 0; s < 4; ++s) {
            int q = t + s * 512; int row = q >> 3, c8 = (q & 7) << 3;
            *(uint4*)(&As[row][c8]) = *(const uint4*)(Wvb + ((size_t)(oc0 + row) << 9) + ks + c8);
        }
        #pragma unroll
        for (int s = 0; s < 2; ++s) {
            int q = t + s * 512; int row = q >> 3, c8 = (q & 7) << 3;
            *(uint4*)(&Bs[row][c8]) = *(const uint4*)(xT + ((size_t)(p0 + row) << 9) + ks + c8);
        }
        __syncthreads();
        #pragma unroll
        for (int kk = 0; kk < 2; ++kk) {
            int ko = (kk << 5) + ((lane >> 4) << 3);
            short8 af[4], bfv[4];
            #pragma unroll
            for (int m = 0; m < 4; ++m) af[m] = *(const short8*)(&As[wr * 64 + m * 16 + (lane & 15)][ko]);
            #pragma unroll
            for (int n = 0; n < 4; ++n) bfv[n] = *(const short8*)(&Bs[wc * 64 + n * 16 + (lane & 15)][ko]);
            #pragma unroll
            for (int m = 0; m < 4; ++m)
                #pragma unroll
                for (int n = 0; n < 4; ++n)
                    acc[m][n] = __builtin_amdgcn_mfma_f32_16x16x32_bf16(af[m], bfv[n], acc[m][n], 0, 0, 0);
        }
        __syncthreads();
    }
    int b = p0 / HW_;
    int hw0 = p0 - b * HW_;
    #pragma unroll
    for (int m = 0; m < 4; ++m) {
        int ocb = oc0 + wr * 64 + m * 16 + ((lane >> 4) << 2);
        #pragma unroll
        for (int n = 0; n < 4; ++n) {
            int hw = hw0 + wc * 64 + n * 16 + (lane & 15);
            #pragma unroll
            for (int r = 0; r < 4; ++r) {
                int oc = ocb + r;
                Vn[(size_t)(b * C_ + oc) * HW_ + hw] = f2bf(acc[m][n][r] + bv[oc]);
            }
        }
    }
}

// ---------------- K3: Vn[b][c][h][w] -> Vt[b][c][w][h] (bf16 plane transpose) ----------------
__global__ __launch_bounds__(256) void k3_vt(const unsigned short* __restrict__ Vn,
                                             unsigned short* __restrict__ Vt) {
    __shared__ unsigned short tl[96][97];
    int plane = blockIdx.x;                         // b*512+c
    const unsigned short* src = Vn + (size_t)plane * HW_;
    unsigned short* dst = Vt + (size_t)plane * HW_;
    for (int e = threadIdx.x; e < HW_; e += 256) tl[e / 96][e % 96] = src[e];
    __syncthreads();
    for (int e = threadIdx.x; e < HW_; e += 256) { int w = e / 96, h = e % 96; dst[e] = tl[h][w]; }
}

// ---------------- K4: energies (fp16 out). z=0: E_W per (b,h); z=1: E_H per (b,w), diag=-inf ----------------
__global__ __launch_bounds__(256) void k4_energy(const unsigned short* __restrict__ Qb,
                                                 const unsigned short* __restrict__ Kb,
                                                 unsigned short* __restrict__ att) {
    __shared__ alignas(16) unsigned short Qs[96][136];
    __shared__ alignas(16) unsigned short Ks[96][136];
    int t = threadIdx.x;
    int modeH = blockIdx.z;
    int b = blockIdx.y, v0 = blockIdx.x;
    size_t base, rstride, obase_off, ostride;
    if (!modeH) {               // rows i=w at fixed (b,h=v0)
        base      = (size_t)((b * H_ + v0) * W_) * CQ_;
        rstride   = CQ_;
        obase_off = (size_t)((b * H_ + v0) * W_) * J_ + H_;   // att[b][v0][i][96+j]
        ostride   = J_;
    } else {                    // rows i=h at fixed (b,w=v0)
        base      = ((size_t)(b * H_) * W_ + v0) * CQ_;
        rstride   = (size_t)W_ * CQ_;
        obase_off = ((size_t)(b * H_) * W_ + v0) * J_;        // att[b][i][v0][j]
        ostride   = (size_t)W_ * J_;
    }
    for (int q = t; q < 1536; q += 256) {
        int row = q >> 4, c8 = (q & 15) << 3;
        *(uint4*)(&Qs[row][c8]) = *(const uint4*)(Qb + base + (size_t)row * rstride + c8);
        *(uint4*)(&Ks[row][c8]) = *(const uint4*)(Kb + base + (size_t)row * rstride + c8);
    }
    __syncthreads();
    int wid = t >> 6, lane = t & 63;
    int wr = wid >> 1, wc = wid & 1;                 // 2x2 waves of 48x48
    const f32x4 zero = {0.f, 0.f, 0.f, 0.f};
    f32x4 acc[3][3];
    for (int m = 0; m < 3; ++m) for (int n = 0; n < 3; ++n) acc[m][n] = zero;
    #pragma unroll
    for (int ks = 0; ks < 128; ks += 32) {
        int ko = ks + ((lane >> 4) << 3);
        short8 af[3], bfv[3];
        #pragma unroll
        for (int m = 0; m < 3; ++m) af[m] = *(const short8*)(&Qs[wr * 48 + m * 16 + (lane & 15)][ko]);
        #pragma unroll
        for (int n = 0; n < 3; ++n) bfv[n] = *(const short8*)(&Ks[wc * 48 + n * 16 + (lane & 15)][ko]);
        #pragma unroll
        for (int m = 0; m < 3; ++m)
            #pragma unroll
            for (int n = 0; n < 3; ++n)
                acc[m][n] = __builtin_amdgcn_mfma_f32_16x16x32_bf16(af[m], bfv[n], acc[m][n], 0, 0, 0);
    }
    unsigned short* ob = att + obase_off;
    #pragma unroll
    for (int m = 0; m < 3; ++m) {
        int i = wr * 48 + m * 16 + ((lane >> 4) << 2);
        #pragma unroll
        for (int n = 0; n < 3; ++n) {
            int j = wc * 48 + n * 16 + (lane & 15);
            #pragma unroll
            for (int r = 0; r < 4; ++r) {
                float v = acc[m][n][r];
                if (modeH && (i + r) == j) v = -__builtin_inff();
                ob[(size_t)(i + r) * ostride + j] = f2h(v);
            }
        }
    }
}

// ---------------- K5: softmax over 192 (fp16 in) -> bf16 att2 (one wave per row) ----------------
__global__ __launch_bounds__(256) void k5_softmax(const unsigned short* __restrict__ att,
                                                  unsigned short* __restrict__ att2) {
    int r = blockIdx.x * 4 + (threadIdx.x >> 6);
    int lane = threadIdx.x & 63;
    const unsigned short* row = att + (size_t)r * J_;
    float e0 = h2f(row[lane]), e1 = h2f(row[lane + 64]), e2 = h2f(row[lane + 128]);
    float m = fmaxf(e0, fmaxf(e1, e2));
    #pragma unroll
    for (int off = 32; off; off >>= 1) m = fmaxf(m, __shfl_xor(m, off, 64));
    float p0 = __expf(e0 - m), p1 = __expf(e1 - m), p2 = __expf(e2 - m);
    float s = p0 + p1 + p2;
    #pragma unroll
    for (int off = 32; off; off >>= 1) s += __shfl_xor(s, off, 64);
    float inv = 1.f / s;
    unsigned short* orow = att2 + (size_t)r * J_;
    orow[lane]       = f2bf(p0 * inv);
    orow[lane + 64]  = f2bf(p1 * inv);
    orow[lane + 128] = f2bf(p2 * inv);
}

// ---------------- K6/K7: aggregation GEMMs (IN-PLACE over Vsrc), M=512(c) N=96 K=96 per (b, h|w) ----------------
// MODE 0: out_W per (b,h): dst rows = Vn rows (c, fixed h)      -> tmpW[b][c][h][w]
// MODE 1: out_H per (b,w): dst rows = Vt rows (c, fixed w)      -> tmpHT[b][c][w][h]
// Safe in-place: each block stages its A rows to LDS before the barrier, blocks own disjoint rows.
template <int MODE>
__global__ __launch_bounds__(256) void k67_agg(const unsigned short* __restrict__ Vsrc,
                                               const unsigned short* __restrict__ att2,
                                               unsigned short* __restrict__ dst) {
    __shared__ alignas(16) unsigned short As[128][104];
    __shared__ alignas(16) unsigned short Bs[96][104];
    int t = threadIdx.x;
    int c0 = blockIdx.x * 128;
    int b = blockIdx.y / 96;
    int v0 = blockIdx.y % 96;
    size_t abase, bbase, bstride;
    if (MODE == 0) {
        abase = (size_t)(b * C_ + c0) * HW_ + (size_t)v0 * W_;
        bbase = (size_t)((b * H_ + v0) * W_) * J_ + H_;
        bstride = J_;
    } else {
        abase = ((size_t)(b * C_ + c0) * W_ + v0) * H_;
        bbase = ((size_t)(b * H_) * W_ + v0) * J_;
        bstride = (size_t)W_ * J_;
    }
    {
        int row = t >> 1, cs = (t & 1) * 6;
        const unsigned short* src = Vsrc + abase + (size_t)row * HW_;
        #pragma unroll
        for (int i = 0; i < 6; ++i)
            *(uint4*)(&As[row][(cs + i) * 8]) = *(const uint4*)(src + (cs + i) * 8);
    }
    if (t < 192) {
        int row = t >> 1, cs = (t & 1) * 6;
        const unsigned short* src = att2 + bbase + (size_t)row * bstride;
        #pragma unroll
        for (int i = 0; i < 6; ++i)
            *(uint4*)(&Bs[row][(cs + i) * 8]) = *(const uint4*)(src + (cs + i) * 8);
    }
    __syncthreads();
    int wid = t >> 6, lane = t & 63;               // 4 waves, each 32 rows x 96 cols
    const f32x4 zero = {0.f, 0.f, 0.f, 0.f};
    f32x4 acc[2][6];
    for (int m = 0; m < 2; ++m) for (int n = 0; n < 6; ++n) acc[m][n] = zero;
    #pragma unroll
    for (int ks = 0; ks < 96; ks += 32) {
        int ko = ks + ((lane >> 4) << 3);
        short8 af[2], bfv[6];
        #pragma unroll
        for (int m = 0; m < 2; ++m) af[m] = *(const short8*)(&As[wid * 32 + m * 16 + (lane & 15)][ko]);
        #pragma unroll
        for (int n = 0; n < 6; ++n) bfv[n] = *(const short8*)(&Bs[n * 16 + (lane & 15)][ko]);
        #pragma unroll
        for (int m = 0; m < 2; ++m)
            #pragma unroll
            for (int n = 0; n < 6; ++n)
                acc[m][n] = __builtin_amdgcn_mfma_f32_16x16x32_bf16(af[m], bfv[n], acc[m][n], 0, 0, 0);
    }
    #pragma unroll
    for (int m = 0; m < 2; ++m) {
        int crel = wid * 32 + m * 16 + ((lane >> 4) << 2);
        #pragma unroll
        for (int n = 0; n < 6; ++n) {
            int col = n * 16 + (lane & 15);
            #pragma unroll
            for (int r = 0; r < 4; ++r)
                dst[abase + (size_t)(crel + r) * HW_ + col] = f2bf(acc[m][n][r]);
        }
    }
}

// ---------------- K8b: out[b][c][h][w] = g*(tmpW[b][c][h][w] + tmpHT[b][c][w][h]) + x ----------------
__global__ __launch_bounds__(256) void k8b_combine(const unsigned short* __restrict__ tmpW,
                                                   const unsigned short* __restrict__ tmpHT,
                                                   const float* __restrict__ x,
                                                   const float* __restrict__ gamma_p,
                                                   float* __restrict__ outp) {
    __shared__ unsigned tlp[96][49];                 // [w][h/2] packed bf16 pairs
    int plane = blockIdx.x;                          // b*512+c
    int t = threadIdx.x;
    const unsigned short* src = tmpHT + (size_t)plane * HW_;   // [w][h]
    for (int e = t; e < 1152; e += 256) {            // 1152 = 9216/8
        int w = e / 12, h8 = (e % 12) * 8;
        uint4 v = *(const uint4*)(src + w * 96 + h8);
        tlp[w][(h8 >> 1) + 0] = v.x;
        tlp[w][(h8 >> 1) + 1] = v.y;
        tlp[w][(h8 >> 1) + 2] = v.z;
        tlp[w][(h8 >> 1) + 3] = v.w;
    }
    __syncthreads();
    float g = gamma_p[0];
    const unsigned short* wp = tmpW + (size_t)plane * HW_;
    const float* xp = x + (size_t)plane * HW_;
    float* op = outp + (size_t)plane * HW_;
    #pragma unroll
    for (int i = 0; i < 9; ++i) {                    // 2304 float4 groups
        int m = t + 256 * i;
        int h = m / 24, w0 = (m % 24) * 4;
        int off = h * 96 + w0;
        f32x4 xv = *(const f32x4*)(xp + off);
        uint2 tw = *(const uint2*)(wp + off);        // 4 bf16 (w0..w0+3 at row h)
        unsigned short ws0 = (unsigned short)(tw.x & 0xFFFF);
        unsigned short ws1 = (unsigned short)(tw.x >> 16);
        unsigned short ws2 = (unsigned short)(tw.y & 0xFFFF);
        unsigned short ws3 = (unsigned short)(tw.y >> 16);
        f32x4 o;
        #pragma unroll
        for (int r = 0; r < 4; ++r) {
            unsigned u = tlp[w0 + r][h >> 1];
            unsigned short hv = (h & 1) ? (unsigned short)(u >> 16) : (unsigned short)(u & 0xFFFF);
            unsigned short wv = (r == 0) ? ws0 : (r == 1) ? ws1 : (r == 2) ? ws2 : ws3;
            o[r] = g * (bf2f(wv) + bf2f(hv)) + xv[r];
        }
        *(f32x4*)(op + off) = o;
    }
}

extern "C" void kernel_launch(void* const* d_in, const int* in_sizes, int n_in,
                              void* d_out, int out_size, void* d_ws, size_t ws_size,
                              hipStream_t stream) {
    const float* x  = (const float*)d_in[0];
    const float* Wq = (const float*)d_in[1];
    const float* bq = (const float*)d_in[2];
    const float* Wk = (const float*)d_in[3];
    const float* bk = (const float*)d_in[4];
    const float* Wv = (const float*)d_in[5];
    const float* bv = (const float*)d_in[6];
    const float* gm = (const float*)d_in[7];
    float* out = (float*)d_out;
    char* ws = (char*)d_ws;

    unsigned short* xT    = (unsigned short*)(ws + 0);
    unsigned short* attf  = (unsigned short*)(ws + 0);           // fp16, after k2b done
    unsigned short* Vt    = (unsigned short*)(ws + 0);           // after k5 done; tmpHT in-place
    unsigned short* Vn    = (unsigned short*)(ws + 75497472);    // tmpW in-place
    unsigned short* Qb    = (unsigned short*)(ws + 150994944);
    unsigned short* Kb    = (unsigned short*)(ws + 169869312);
    unsigned short* att2  = (unsigned short*)(ws + 150994944);   // after k4 done
    unsigned short* Wqk   = (unsigned short*)(ws + 188743680);
    unsigned short* Wvb   = (unsigned short*)(ws + 189005824);
    // total ws need: 189,530,112 bytes

    k0_wconv<<<1536, 256, 0, stream>>>(Wq, Wk, Wv, Wqk, Wvb);
    k1_xT<<<dim3(288, 16, 8), dim3(32, 8, 1), 0, stream>>>(x, xT);
    k2a_qk<<<576, 512, 0, stream>>>(xT, Wqk, bq, bk, Qb, Kb);
    k2b_v<<<dim3(2, 576), 512, 0, stream>>>(xT, Wvb, bv, Vn);
    k4_energy<<<dim3(96, 8, 2), 256, 0, stream>>>(Qb, Kb, attf);   // attf overwrites xT (dead)
    k5_softmax<<<18432, 256, 0, stream>>>(attf, att2);             // att2 overwrites Q/K (dead)
    k3_vt<<<4096, 256, 0, stream>>>(Vn, Vt);                       // Vt overwrites attf (dead)
    k67_agg<0><<<dim3(4, 768), 256, 0, stream>>>(Vn, att2, Vn);    // tmpW in-place over Vn
    k67_agg<1><<<dim3(4, 768), 256, 0, stream>>>(Vt, att2, Vt);    // tmpHT in-place over Vt
    k8b_combine<<<4096, 256, 0, stream>>>(Vn, Vt, x, gm, out);
}

// Round 3
// 378.964 us; speedup vs baseline: 1.2206x; 1.0293x over previous
//
#include <hip/hip_runtime.h>

// CrissCrossAttention: B=8 C=512 CQ=128 H=W=96
// ws layout (bytes), total 189,530,112 (overlaid, launch order enforces lifetimes):
//  R0 @0         (75,497,472): xT[b][hw][c]bf16 -> att_f16[b][h][w][192] -> Vt[b][c][w][h]bf16 -> tmpHT (in-place)
//  R1 @75497472  (75,497,472): Vn[b][c][h][w]bf16 -> tmpW (in-place)
//  R2 @150994944 (37,748,736): Qb[p][128]bf16 | Kb[p][128]bf16 -> att2[b][h][w][192]bf16
//  R3 @188743680 (   786,432): Wqk bf16[256][512], Wv bf16[512][512]

#define B_ 8
#define C_ 512
#define CQ_ 128
#define H_ 96
#define W_ 96
#define HW_ 9216
#define J_ 192

typedef __attribute__((ext_vector_type(8))) short short8;
typedef __attribute__((ext_vector_type(4))) float f32x4;

__device__ __forceinline__ unsigned short f2bf(float f) {
    unsigned u = __float_as_uint(f);
    u += 0x7FFFu + ((u >> 16) & 1u);
    return (unsigned short)(u >> 16);
}
__device__ __forceinline__ float bf2f(unsigned short h) {
    return __uint_as_float((unsigned)h << 16);
}
__device__ __forceinline__ unsigned short f2h(float f) {
    _Float16 h = (_Float16)f;
    return __builtin_bit_cast(unsigned short, h);
}
__device__ __forceinline__ float h2f(unsigned short u) {
    return (float)__builtin_bit_cast(_Float16, u);
}
// async global->LDS, 16B per lane; lds base must be wave-uniform (HW adds lane*16)
__device__ __forceinline__ void gl_lds16(const unsigned short* g, void* lds_base) {
    __builtin_amdgcn_global_load_lds((const __attribute__((address_space(1))) void*)g,
                                     (__attribute__((address_space(3))) void*)lds_base,
                                     16, 0, 0);
}

// ---------------- K0: weights fp32 -> bf16 (fused Wq|Wk, Wv) ----------------
__global__ __launch_bounds__(256) void k0_wconv(const float* __restrict__ Wq,
                                                const float* __restrict__ Wk,
                                                const float* __restrict__ Wv,
                                                unsigned short* __restrict__ Wqk,
                                                unsigned short* __restrict__ Wvb) {
    int i = blockIdx.x * 256 + threadIdx.x;          // grid 1536*256 = 393216 exact
    if (i < 65536)        Wqk[i] = f2bf(Wq[i]);
    else if (i < 131072)  Wqk[i] = f2bf(Wk[i - 65536]);
    else                  Wvb[i - 131072] = f2bf(Wv[i - 131072]);
}

// ---------------- K1: x[b][c][h][w] f32 -> xT[b][hw][c] bf16 ----------------
__global__ __launch_bounds__(256) void k1_xT(const float* __restrict__ x,
                                             unsigned short* __restrict__ xT) {
    __shared__ unsigned short t[32][33];
    int b = blockIdx.z, c0 = blockIdx.y * 32, p0 = blockIdx.x * 32;
    int tx = threadIdx.x, ty = threadIdx.y;
    const float* xb = x + (size_t)b * C_ * HW_;
    #pragma unroll
    for (int k = 0; k < 4; ++k) {
        int c = c0 + ty + k * 8;
        t[ty + k * 8][tx] = f2bf(xb[(size_t)c * HW_ + p0 + tx]);
    }
    __syncthreads();
    unsigned short* xTb = xT + (size_t)b * HW_ * C_;
    #pragma unroll
    for (int k = 0; k < 4; ++k) {
        int p = p0 + ty + k * 8;
        xTb[(size_t)p * C_ + c0 + tx] = t[tx][ty + k * 8];
    }
}

// ---------------- K2a: Q,K projection. D[p][oc]=sum_c xT[p][c]*Wqk[oc][c]+b ----------------
// BM=128(p) BN=256(oc) BK=64, 8 waves (2x4 of 64x64), global_load_lds staging
__global__ __launch_bounds__(512) void k2a_qk(const unsigned short* __restrict__ xT,
                                              const unsigned short* __restrict__ Wqk,
                                              const float* __restrict__ bq,
                                              const float* __restrict__ bk,
                                              unsigned short* __restrict__ Qb,
                                              unsigned short* __restrict__ Kb) {
    __shared__ alignas(16) unsigned short As[128][64];   // 16 KB, linear (gl_lds dest)
    __shared__ alignas(16) unsigned short Bs[256][64];   // 32 KB
    int t = threadIdx.x;
    int p0 = blockIdx.x * 128;
    int wid = t >> 6, lane = t & 63;
    int wr = wid >> 2, wc = wid & 3;
    int srow = lane >> 3, sk8 = (lane & 7) << 3;         // within-chunk row/col
    const f32x4 zero = {0.f, 0.f, 0.f, 0.f};
    f32x4 acc[4][4];
    for (int m = 0; m < 4; ++m) for (int n = 0; n < 4; ++n) acc[m][n] = zero;
    for (int ks = 0; ks < 512; ks += 64) {
        #pragma unroll
        for (int i = 0; i < 2; ++i) {                    // A: 16 chunks of 1KB, 2/wave
            int q = wid * 2 + i; int row = q * 8 + srow;
            gl_lds16(xT + ((size_t)(p0 + row) << 9) + ks + sk8, (char*)&As[0][0] + q * 1024);
        }
        #pragma unroll
        for (int i = 0; i < 4; ++i) {                    // B: 32 chunks, 4/wave
            int q = wid * 4 + i; int row = q * 8 + srow;
            gl_lds16(Wqk + ((size_t)row << 9) + ks + sk8, (char*)&Bs[0][0] + q * 1024);
        }
        __syncthreads();                                  // drains vmcnt -> LDS ready
        #pragma unroll
        for (int kk = 0; kk < 2; ++kk) {
            int ko = (kk << 5) + ((lane >> 4) << 3);
            short8 af[4], bfv[4];
            #pragma unroll
            for (int m = 0; m < 4; ++m) af[m] = *(const short8*)(&As[wr * 64 + m * 16 + (lane & 15)][ko]);
            #pragma unroll
            for (int n = 0; n < 4; ++n) bfv[n] = *(const short8*)(&Bs[wc * 64 + n * 16 + (lane & 15)][ko]);
            #pragma unroll
            for (int m = 0; m < 4; ++m)
                #pragma unroll
                for (int n = 0; n < 4; ++n)
                    acc[m][n] = __builtin_amdgcn_mfma_f32_16x16x32_bf16(af[m], bfv[n], acc[m][n], 0, 0, 0);
        }
        __syncthreads();                                  // all reads done before re-stage
    }
    #pragma unroll
    for (int n = 0; n < 4; ++n) {
        int oc = wc * 64 + n * 16 + (lane & 15);
        float bias = (oc < 128) ? bq[oc] : bk[oc - 128];
        unsigned short* dst = (oc < 128) ? (Qb + oc) : (Kb + (oc - 128));
        #pragma unroll
        for (int m = 0; m < 4; ++m) {
            int pr = p0 + wr * 64 + m * 16 + ((lane >> 4) << 2);
            #pragma unroll
            for (int r = 0; r < 4; ++r)
                dst[(size_t)(pr + r) << 7] = f2bf(acc[m][n][r] + bias);
        }
    }
}

// ---------------- K2b: V projection. D[oc][p]=sum_c Wv[oc][c]*xT[p][c]+bv -> Vn[b][c][hw] ----------------
// BM=512(oc, all) BN=64(p) BK=64, 8 waves (4x2 of 128x32), global_load_lds staging.
// xT read exactly once across the grid; Wv (512KB bf16) stays L2/L3-hot.
__global__ __launch_bounds__(512) void k2b_v(const unsigned short* __restrict__ xT,
                                             const unsigned short* __restrict__ Wvb,
                                             const float* __restrict__ bv,
                                             unsigned short* __restrict__ Vn) {
    __shared__ alignas(16) unsigned short As[512][64];   // Wv tile, 64 KB
    __shared__ alignas(16) unsigned short Bs[64][64];    // xT tile, 8 KB
    int t = threadIdx.x;
    int p0 = blockIdx.x * 64;                            // grid 1152
    int wid = t >> 6, lane = t & 63;
    int wr = wid >> 1, wc = wid & 1;                     // 4(oc:128) x 2(p:32)
    int srow = lane >> 3, sk8 = (lane & 7) << 3;
    const f32x4 zero = {0.f, 0.f, 0.f, 0.f};
    f32x4 acc[8][2];
    for (int m = 0; m < 8; ++m) for (int n = 0; n < 2; ++n) acc[m][n] = zero;
    for (int ks = 0; ks < 512; ks += 64) {
        #pragma unroll
        for (int i = 0; i < 8; ++i) {                    // A: 64 chunks, 8/wave
            int q = wid * 8 + i; int row = q * 8 + srow;
            gl_lds16(Wvb + ((size_t)row << 9) + ks + sk8, (char*)&As[0][0] + q * 1024);
        }
        {                                                 // B: 8 chunks, 1/wave
            int q = wid; int row = q * 8 + srow;
            gl_lds16(xT + ((size_t)(p0 + row) << 9) + ks + sk8, (char*)&Bs[0][0] + q * 1024);
        }
        __syncthreads();
        #pragma unroll
        for (int kk = 0; kk < 2; ++kk) {
            int ko = (kk << 5) + ((lane >> 4) << 3);
            short8 af[8], bfv[2];
            #pragma unroll
            for (int m = 0; m < 8; ++m) af[m] = *(const short8*)(&As[wr * 128 + m * 16 + (lane & 15)][ko]);
            #pragma unroll
            for (int n = 0; n < 2; ++n) bfv[n] = *(const short8*)(&Bs[wc * 32 + n * 16 + (lane & 15)][ko]);
            #pragma unroll
            for (int m = 0; m < 8; ++m)
                #pragma unroll
                for (int n = 0; n < 2; ++n)
                    acc[m][n] = __builtin_amdgcn_mfma_f32_16x16x32_bf16(af[m], bfv[n], acc[m][n], 0, 0, 0);
        }
        __syncthreads();
    }
    int b = p0 / HW_;
    int hw0 = p0 - b * HW_;
    #pragma unroll
    for (int m = 0; m < 8; ++m) {
        int ocb = wr * 128 + m * 16 + ((lane >> 4) << 2);
        #pragma unroll
        for (int n = 0; n < 2; ++n) {
            int hw = hw0 + wc * 32 + n * 16 + (lane & 15);
            #pragma unroll
            for (int r = 0; r < 4; ++r) {
                int oc = ocb + r;
                Vn[(size_t)(b * C_ + oc) * HW_ + hw] = f2bf(acc[m][n][r] + bv[oc]);
            }
        }
    }
}

// ---------------- K3: Vn[b][c][h][w] -> Vt[b][c][w][h] (bf16 plane transpose) ----------------
__global__ __launch_bounds__(256) void k3_vt(const unsigned short* __restrict__ Vn,
                                             unsigned short* __restrict__ Vt) {
    __shared__ unsigned short tl[96][97];
    int plane = blockIdx.x;                         // b*512+c
    const unsigned short* src = Vn + (size_t)plane * HW_;
    unsigned short* dst = Vt + (size_t)plane * HW_;
    for (int e = threadIdx.x; e < HW_; e += 256) tl[e / 96][e % 96] = src[e];
    __syncthreads();
    for (int e = threadIdx.x; e < HW_; e += 256) { int w = e / 96, h = e % 96; dst[e] = tl[h][w]; }
}

// ---------------- K4: energies (fp16 out). z=0: E_W per (b,h); z=1: E_H per (b,w), diag=-inf ----------------
__global__ __launch_bounds__(256) void k4_energy(const unsigned short* __restrict__ Qb,
                                                 const unsigned short* __restrict__ Kb,
                                                 unsigned short* __restrict__ att) {
    __shared__ alignas(16) unsigned short Qs[96][136];
    __shared__ alignas(16) unsigned short Ks[96][136];
    int t = threadIdx.x;
    int modeH = blockIdx.z;
    int b = blockIdx.y, v0 = blockIdx.x;
    size_t base, rstride, obase_off, ostride;
    if (!modeH) {               // rows i=w at fixed (b,h=v0)
        base      = (size_t)((b * H_ + v0) * W_) * CQ_;
        rstride   = CQ_;
        obase_off = (size_t)((b * H_ + v0) * W_) * J_ + H_;   // att[b][v0][i][96+j]
        ostride   = J_;
    } else {                    // rows i=h at fixed (b,w=v0)
        base      = ((size_t)(b * H_) * W_ + v0) * CQ_;
        rstride   = (size_t)W_ * CQ_;
        obase_off = ((size_t)(b * H_) * W_ + v0) * J_;        // att[b][i][v0][j]
        ostride   = (size_t)W_ * J_;
    }
    for (int q = t; q < 1536; q += 256) {
        int row = q >> 4, c8 = (q & 15) << 3;
        *(uint4*)(&Qs[row][c8]) = *(const uint4*)(Qb + base + (size_t)row * rstride + c8);
        *(uint4*)(&Ks[row][c8]) = *(const uint4*)(Kb + base + (size_t)row * rstride + c8);
    }
    __syncthreads();
    int wid = t >> 6, lane = t & 63;
    int wr = wid >> 1, wc = wid & 1;                 // 2x2 waves of 48x48
    const f32x4 zero = {0.f, 0.f, 0.f, 0.f};
    f32x4 acc[3][3];
    for (int m = 0; m < 3; ++m) for (int n = 0; n < 3; ++n) acc[m][n] = zero;
    #pragma unroll
    for (int ks = 0; ks < 128; ks += 32) {
        int ko = ks + ((lane >> 4) << 3);
        short8 af[3], bfv[3];
        #pragma unroll
        for (int m = 0; m < 3; ++m) af[m] = *(const short8*)(&Qs[wr * 48 + m * 16 + (lane & 15)][ko]);
        #pragma unroll
        for (int n = 0; n < 3; ++n) bfv[n] = *(const short8*)(&Ks[wc * 48 + n * 16 + (lane & 15)][ko]);
        #pragma unroll
        for (int m = 0; m < 3; ++m)
            #pragma unroll
            for (int n = 0; n < 3; ++n)
                acc[m][n] = __builtin_amdgcn_mfma_f32_16x16x32_bf16(af[m], bfv[n], acc[m][n], 0, 0, 0);
    }
    unsigned short* ob = att + obase_off;
    #pragma unroll
    for (int m = 0; m < 3; ++m) {
        int i = wr * 48 + m * 16 + ((lane >> 4) << 2);
        #pragma unroll
        for (int n = 0; n < 3; ++n) {
            int j = wc * 48 + n * 16 + (lane & 15);
            #pragma unroll
            for (int r = 0; r < 4; ++r) {
                float v = acc[m][n][r];
                if (modeH && (i + r) == j) v = -__builtin_inff();
                ob[(size_t)(i + r) * ostride + j] = f2h(v);
            }
        }
    }
}

// ---------------- K5: softmax over 192 (fp16 in) -> bf16 att2 (one wave per row) ----------------
__global__ __launch_bounds__(256) void k5_softmax(const unsigned short* __restrict__ att,
                                                  unsigned short* __restrict__ att2) {
    int r = blockIdx.x * 4 + (threadIdx.x >> 6);
    int lane = threadIdx.x & 63;
    const unsigned short* row = att + (size_t)r * J_;
    float e0 = h2f(row[lane]), e1 = h2f(row[lane + 64]), e2 = h2f(row[lane + 128]);
    float m = fmaxf(e0, fmaxf(e1, e2));
    #pragma unroll
    for (int off = 32; off; off >>= 1) m = fmaxf(m, __shfl_xor(m, off, 64));
    float p0 = __expf(e0 - m), p1 = __expf(e1 - m), p2 = __expf(e2 - m);
    float s = p0 + p1 + p2;
    #pragma unroll
    for (int off = 32; off; off >>= 1) s += __shfl_xor(s, off, 64);
    float inv = 1.f / s;
    unsigned short* orow = att2 + (size_t)r * J_;
    orow[lane]       = f2bf(p0 * inv);
    orow[lane + 64]  = f2bf(p1 * inv);
    orow[lane + 128] = f2bf(p2 * inv);
}

// ---------------- K6/K7: aggregation GEMMs (IN-PLACE over Vsrc), M=512(c) N=96 K=96 per (b, h|w) ----------------
// MODE 0: out_W per (b,h): dst rows = Vn rows (c, fixed h)      -> tmpW[b][c][h][w]
// MODE 1: out_H per (b,w): dst rows = Vt rows (c, fixed w)      -> tmpHT[b][c][w][h]
// Safe in-place: each block stages its A rows to LDS before the barrier, blocks own disjoint rows.
template <int MODE>
__global__ __launch_bounds__(256) void k67_agg(const unsigned short* __restrict__ Vsrc,
                                               const unsigned short* __restrict__ att2,
                                               unsigned short* __restrict__ dst) {
    __shared__ alignas(16) unsigned short As[128][104];
    __shared__ alignas(16) unsigned short Bs[96][104];
    int t = threadIdx.x;
    int c0 = blockIdx.x * 128;
    int b = blockIdx.y / 96;
    int v0 = blockIdx.y % 96;
    size_t abase, bbase, bstride;
    if (MODE == 0) {
        abase = (size_t)(b * C_ + c0) * HW_ + (size_t)v0 * W_;
        bbase = (size_t)((b * H_ + v0) * W_) * J_ + H_;
        bstride = J_;
    } else {
        abase = ((size_t)(b * C_ + c0) * W_ + v0) * H_;
        bbase = ((size_t)(b * H_) * W_ + v0) * J_;
        bstride = (size_t)W_ * J_;
    }
    {
        int row = t >> 1, cs = (t & 1) * 6;
        const unsigned short* src = Vsrc + abase + (size_t)row * HW_;
        #pragma unroll
        for (int i = 0; i < 6; ++i)
            *(uint4*)(&As[row][(cs + i) * 8]) = *(const uint4*)(src + (cs + i) * 8);
    }
    if (t < 192) {
        int row = t >> 1, cs = (t & 1) * 6;
        const unsigned short* src = att2 + bbase + (size_t)row * bstride;
        #pragma unroll
        for (int i = 0; i < 6; ++i)
            *(uint4*)(&Bs[row][(cs + i) * 8]) = *(const uint4*)(src + (cs + i) * 8);
    }
    __syncthreads();
    int wid = t >> 6, lane = t & 63;               // 4 waves, each 32 rows x 96 cols
    const f32x4 zero = {0.f, 0.f, 0.f, 0.f};
    f32x4 acc[2][6];
    for (int m = 0; m < 2; ++m) for (int n = 0; n < 6; ++n) acc[m][n] = zero;
    #pragma unroll
    for (int ks = 0; ks < 96; ks += 32) {
        int ko = ks + ((lane >> 4) << 3);
        short8 af[2], bfv[6];
        #pragma unroll
        for (int m = 0; m < 2; ++m) af[m] = *(const short8*)(&As[wid * 32 + m * 16 + (lane & 15)][ko]);
        #pragma unroll
        for (int n = 0; n < 6; ++n) bfv[n] = *(const short8*)(&Bs[n * 16 + (lane & 15)][ko]);
        #pragma unroll
        for (int m = 0; m < 2; ++m)
            #pragma unroll
            for (int n = 0; n < 6; ++n)
                acc[m][n] = __builtin_amdgcn_mfma_f32_16x16x32_bf16(af[m], bfv[n], acc[m][n], 0, 0, 0);
    }
    #pragma unroll
    for (int m = 0; m < 2; ++m) {
        int crel = wid * 32 + m * 16 + ((lane >> 4) << 2);
        #pragma unroll
        for (int n = 0; n < 6; ++n) {
            int col = n * 16 + (lane & 15);
            #pragma unroll
            for (int r = 0; r < 4; ++r)
                dst[abase + (size_t)(crel + r) * HW_ + col] = f2bf(acc[m][n][r]);
        }
    }
}

// ---------------- K8b: out[b][c][h][w] = g*(tmpW[b][c][h][w] + tmpHT[b][c][w][h]) + x ----------------
__global__ __launch_bounds__(256) void k8b_combine(const unsigned short* __restrict__ tmpW,
                                                   const unsigned short* __restrict__ tmpHT,
                                                   const float* __restrict__ x,
                                                   const float* __restrict__ gamma_p,
                                                   float* __restrict__ outp) {
    __shared__ unsigned tlp[96][49];                 // [w][h/2] packed bf16 pairs
    int plane = blockIdx.x;                          // b*512+c
    int t = threadIdx.x;
    const unsigned short* src = tmpHT + (size_t)plane * HW_;   // [w][h]
    for (int e = t; e < 1152; e += 256) {            // 1152 = 9216/8
        int w = e / 12, h8 = (e % 12) * 8;
        uint4 v = *(const uint4*)(src + w * 96 + h8);
        tlp[w][(h8 >> 1) + 0] = v.x;
        tlp[w][(h8 >> 1) + 1] = v.y;
        tlp[w][(h8 >> 1) + 2] = v.z;
        tlp[w][(h8 >> 1) + 3] = v.w;
    }
    __syncthreads();
    float g = gamma_p[0];
    const unsigned short* wp = tmpW + (size_t)plane * HW_;
    const float* xp = x + (size_t)plane * HW_;
    float* op = outp + (size_t)plane * HW_;
    #pragma unroll
    for (int i = 0; i < 9; ++i) {                    // 2304 float4 groups
        int m = t + 256 * i;
        int h = m / 24, w0 = (m % 24) * 4;
        int off = h * 96 + w0;
        f32x4 xv = *(const f32x4*)(xp + off);
        uint2 tw = *(const uint2*)(wp + off);        // 4 bf16 (w0..w0+3 at row h)
        unsigned short ws0 = (unsigned short)(tw.x & 0xFFFF);
        unsigned short ws1 = (unsigned short)(tw.x >> 16);
        unsigned short ws2 = (unsigned short)(tw.y & 0xFFFF);
        unsigned short ws3 = (unsigned short)(tw.y >> 16);
        f32x4 o;
        #pragma unroll
        for (int r = 0; r < 4; ++r) {
            unsigned u = tlp[w0 + r][h >> 1];
            unsigned short hv = (h & 1) ? (unsigned short)(u >> 16) : (unsigned short)(u & 0xFFFF);
            unsigned short wv = (r == 0) ? ws0 : (r == 1) ? ws1 : (r == 2) ? ws2 : ws3;
            o[r] = g * (bf2f(wv) + bf2f(hv)) + xv[r];
        }
        *(f32x4*)(op + off) = o;
    }
}

extern "C" void kernel_launch(void* const* d_in, const int* in_sizes, int n_in,
                              void* d_out, int out_size, void* d_ws, size_t ws_size,
                              hipStream_t stream) {
    const float* x  = (const float*)d_in[0];
    const float* Wq = (const float*)d_in[1];
    const float* bq = (const float*)d_in[2];
    const float* Wk = (const float*)d_in[3];
    const float* bk = (const float*)d_in[4];
    const float* Wv = (const float*)d_in[5];
    const float* bv = (const float*)d_in[6];
    const float* gm = (const float*)d_in[7];
    float* out = (float*)d_out;
    char* ws = (char*)d_ws;

    unsigned short* xT    = (unsigned short*)(ws + 0);
    unsigned short* attf  = (unsigned short*)(ws + 0);           // fp16, after k2b done
    unsigned short* Vt    = (unsigned short*)(ws + 0);           // after k5 done; tmpHT in-place
    unsigned short* Vn    = (unsigned short*)(ws + 75497472);    // tmpW in-place
    unsigned short* Qb    = (unsigned short*)(ws + 150994944);
    unsigned short* Kb    = (unsigned short*)(ws + 169869312);
    unsigned short* att2  = (unsigned short*)(ws + 150994944);   // after k4 done
    unsigned short* Wqk   = (unsigned short*)(ws + 188743680);
    unsigned short* Wvb   = (unsigned short*)(ws + 189005824);
    // total ws need: 189,530,112 bytes

    k0_wconv<<<1536, 256, 0, stream>>>(Wq, Wk, Wv, Wqk, Wvb);
    k1_xT<<<dim3(288, 16, 8), dim3(32, 8, 1), 0, stream>>>(x, xT);
    k2a_qk<<<576, 512, 0, stream>>>(xT, Wqk, bq, bk, Qb, Kb);
    k2b_v<<<1152, 512, 0, stream>>>(xT, Wvb, bv, Vn);
    k4_energy<<<dim3(96, 8, 2), 256, 0, stream>>>(Qb, Kb, attf);   // attf overwrites xT (dead)
    k5_softmax<<<18432, 256, 0, stream>>>(attf, att2);             // att2 overwrites Q/K (dead)
    k3_vt<<<4096, 256, 0, stream>>>(Vn, Vt);                       // Vt overwrites attf (dead)
    k67_agg<0><<<dim3(4, 768), 256, 0, stream>>>(Vn, att2, Vn);    // tmpW in-place over Vn
    k67_agg<1><<<dim3(4, 768), 256, 0, stream>>>(Vt, att2, Vt);    // tmpHT in-place over Vt
    k8b_combine<<<4096, 256, 0, stream>>>(Vn, Vt, x, gm, out);
}